// Round 12
// baseline (567.868 us; speedup 1.0000x reference)
//
#include <hip/hip_runtime.h>

#define N_NODES 100000
#define E_EDGES 1000000
#define R_REL   3
#define NBATCH  6250          // N_NODES / 16
#define NBLK    391           // ceil(N_NODES / 256)
#define SEMBLK  782           // semantic grid blocks
#define CNT_BLKS  11721       // 3907 * 3
#define PROJ_BLKS 391
#define A_BLKS    3125        // 800000 / 256
#define FILL_BLKS 3907
#define PULL_BLKS 3125

using bf16x8 = __attribute__((ext_vector_type(8))) short;
using f32x4  = __attribute__((ext_vector_type(4))) float;
using u32x2  = __attribute__((ext_vector_type(2))) unsigned int;

__device__ __forceinline__ float lrelu(float x) { return fmaxf(x, 0.2f * x); }

__device__ __forceinline__ short f2bf(float f) {   // RNE f32->bf16
    unsigned u = __builtin_bit_cast(unsigned, f);
    u += 0x7FFFu + ((u >> 16) & 1u);
    return (short)(u >> 16);
}
__device__ __forceinline__ float bf_lo(unsigned u) {
    return __builtin_bit_cast(float, u << 16);
}
__device__ __forceinline__ float bf_hi(unsigned u) {
    return __builtin_bit_cast(float, u & 0xFFFF0000u);
}
__device__ __forceinline__ float bf2f(unsigned short u) {
    return __builtin_bit_cast(float, ((unsigned)u) << 16);
}

// ---------------------------------------------------------------------------
// Bake bf16 B-fragments for 16x16x32 MFMA (kw, pw full 128x128; lin 4x128).
// ---------------------------------------------------------------------------
__global__ __launch_bounds__(256) void prep_kernel(
    const float* __restrict__ kw, const float* __restrict__ pw,
    const float* __restrict__ lw,
    short* __restrict__ kwB, short* __restrict__ pwB, short* __restrict__ linB)
{
    int idx = blockIdx.x * 256 + threadIdx.x;
    int which, rem;
    if      (idx < 16384) { which = 0; rem = idx; }
    else if (idx < 32768) { which = 1; rem = idx - 16384; }
    else if (idx < 34816) { which = 2; rem = idx - 32768; }
    else return;
    int e = rem & 7, lane = (rem >> 3) & 63, t = rem >> 9;
    int tj = (which == 2) ? 0 : (t >> 2);
    int tk = (which == 2) ? t : (t & 3);
    int j = tj * 16 + (lane & 15);
    int k = tk * 32 + (lane >> 4) * 8 + e;
    const float* src = (which == 0) ? kw : (which == 1) ? pw : lw;
    float v = (which == 2 && j >= 4) ? 0.f : src[j * 128 + k];
    short* dst = (which == 0) ? kwB : (which == 1) ? pwB : linB;
    dst[rem] = f2bf(v);
}

// ---------------------------------------------------------------------------
// proj body (MFMA): h = x @ pw.T + pb, bf16 out. Low-VGPR variant
// (unroll 1 on tj) so it can ride under count without capping occupancy.
// ---------------------------------------------------------------------------
__device__ __forceinline__ void proj_body(
    int bx, const float* __restrict__ x, const short* __restrict__ pwB,
    const float* __restrict__ pb, unsigned short* __restrict__ h_bf)
{
    int wave = threadIdx.x >> 6, lane = threadIdx.x & 63;
    int row16 = lane & 15, kq = lane >> 4;
    for (int b = bx * 4 + wave; b < NBATCH; b += PROJ_BLKS * 4) {
        int nbase = b * 16;
        bf16x8 A[4];
        #pragma unroll
        for (int tk = 0; tk < 4; ++tk) {
            const float* px = x + (size_t)(nbase + row16) * 128 + tk * 32 + kq * 8;
            f32x4 lo = *(const f32x4*)px;
            f32x4 hi = *(const f32x4*)(px + 4);
            bf16x8 a;
            a[0] = f2bf(lo[0]); a[1] = f2bf(lo[1]); a[2] = f2bf(lo[2]); a[3] = f2bf(lo[3]);
            a[4] = f2bf(hi[0]); a[5] = f2bf(hi[1]); a[6] = f2bf(hi[2]); a[7] = f2bf(hi[3]);
            A[tk] = a;
        }
        #pragma unroll 1
        for (int tj = 0; tj < 8; ++tj) {
            f32x4 c = {0.f, 0.f, 0.f, 0.f};
            #pragma unroll
            for (int tk = 0; tk < 4; ++tk) {
                bf16x8 B = *(const bf16x8*)(pwB + ((size_t)(tj * 4 + tk) * 64 + lane) * 8);
                c = __builtin_amdgcn_mfma_f32_16x16x32_bf16(A[tk], B, c, 0, 0, 0);
            }
            int j = tj * 16 + row16;
            float bias = pb[j];
            #pragma unroll
            for (int m = 0; m < 4; ++m) {
                int n = nbase + kq * 4 + m;
                h_bf[(size_t)n * 128 + j] = (unsigned short)f2bf(c[m] + bias);
            }
        }
    }
}

// FUSED count(all r) + proj. (256,6) caps VGPR at ~85 so count keeps ~75%
// occupancy (round-11 lesson: a 112-VGPR rider throttled count 120->146).
__global__ __launch_bounds__(256, 6) void count_proj_kernel(
    const int* __restrict__ e0, const int* __restrict__ e1, const int* __restrict__ e2,
    int* __restrict__ cnt, int* __restrict__ rank,
    const float* __restrict__ x, const short* __restrict__ pwB,
    const float* __restrict__ pb, unsigned short* __restrict__ h_bf)
{
    int b = blockIdx.x;
    if (b < CNT_BLKS) {
        int r = b / 3907, eb = b % 3907;
        const int* ei = (r == 0) ? e0 : (r == 1) ? e1 : e2;
        int e = eb * 256 + threadIdx.x;
        if (e < E_EDGES) {
            int k = atomicAdd(&cnt[r * N_NODES + ei[E_EDGES + e]], 1);
            rank[(size_t)r * E_EDGES + e] = k;
        }
    } else {
        proj_body(b - CNT_BLKS, x, pwB, pb, h_bf);
    }
}

// --------------------------- scans ------------------------------------
__global__ __launch_bounds__(256) void bsum_kernel(
    const int* __restrict__ cnt, int* __restrict__ bsums)
{
    __shared__ int sh[256];
    int r = blockIdx.y, b = blockIdx.x, t = threadIdx.x;
    int i = b * 256 + t;
    sh[t] = (i < N_NODES) ? cnt[r * N_NODES + i] : 0;
    __syncthreads();
    for (int d = 128; d > 0; d >>= 1) {
        if (t < d) sh[t] += sh[t + d];
        __syncthreads();
    }
    if (t == 0) bsums[r * NBLK + b] = sh[0];
}

__global__ __launch_bounds__(512) void bscan_kernel(
    const int* __restrict__ bsums, int* __restrict__ bpre)
{
    __shared__ int sh[512];
    int r = blockIdx.x, t = threadIdx.x;
    sh[t] = (t < NBLK) ? bsums[r * NBLK + t] : 0;
    __syncthreads();
    for (int d = 1; d < 512; d <<= 1) {
        int v = (t >= d) ? sh[t - d] : 0;
        __syncthreads();
        sh[t] += v;
        __syncthreads();
    }
    if (t < NBLK) bpre[r * NBLK + t] = (t > 0) ? sh[t - 1] : 0;
}

__global__ __launch_bounds__(256) void offwrite_kernel(
    const int* __restrict__ cnt, const int* __restrict__ bpre,
    int* __restrict__ off)
{
    __shared__ int sh[256];
    int r = blockIdx.y, b = blockIdx.x, t = threadIdx.x;
    int i = b * 256 + t;
    int c = (i < N_NODES) ? cnt[r * N_NODES + i] : 0;
    sh[t] = c;
    __syncthreads();
    for (int d = 1; d < 256; d <<= 1) {
        int v = (t >= d) ? sh[t - d] : 0;
        __syncthreads();
        sh[t] += v;
        __syncthreads();
    }
    if (i < N_NODES)
        off[r * N_NODES + i] = r * E_EDGES + bpre[r * NBLK + b] + (sh[t] - c);
}

// --------------------------- a / fill bodies -------------------------------
__device__ __forceinline__ void a_body(
    int bx, const unsigned short* __restrict__ h_bf,
    const float* __restrict__ att_src, const float* __restrict__ att_dst,
    float* __restrict__ a_src, float* __restrict__ a_dst)
{
    int idx = bx * 256 + threadIdx.x;
    if (idx >= N_NODES * 8) return;
    int n = idx >> 3, hd = idx & 7;
    float hv[16];
    const unsigned short* ph = h_bf + (size_t)n * 128 + hd * 16;
    #pragma unroll
    for (int d = 0; d < 16; ++d) hv[d] = bf2f(ph[d]);
    #pragma unroll
    for (int r = 0; r < 3; ++r) {
        float vs = 0.f, vd = 0.f;
        #pragma unroll
        for (int d = 0; d < 16; ++d) {
            vs += hv[d] * att_src[(r * 8 + hd) * 16 + d];
            vd += hv[d] * att_dst[(r * 8 + hd) * 16 + d];
        }
        a_src[((size_t)r * N_NODES + n) * 8 + hd] = vs;
        a_dst[((size_t)r * N_NODES + n) * 8 + hd] = vd;
    }
}

__device__ __forceinline__ void fill_body(
    int r, int eb,
    const int* __restrict__ e0, const int* __restrict__ e1, const int* __restrict__ e2,
    const int* __restrict__ off, const int* __restrict__ rank,
    int* __restrict__ csr_rows)
{
    const int* ei = (r == 0) ? e0 : (r == 1) ? e1 : e2;
    int e = eb * 256 + threadIdx.x;
    if (e >= E_EDGES) return;
    int col = ei[E_EDGES + e];
    int pos = off[r * N_NODES + col] + rank[(size_t)r * E_EDGES + e];
    csr_rows[pos] = ei[e];
}

// FUSED a + fill(first nfill relations). Both bodies <=48 VGPR.
__global__ __launch_bounds__(256) void a_fill_kernel(
    const unsigned short* __restrict__ h_bf, const float* __restrict__ att_src,
    const float* __restrict__ att_dst, float* __restrict__ a_src,
    float* __restrict__ a_dst,
    const int* __restrict__ e0, const int* __restrict__ e1, const int* __restrict__ e2,
    const int* __restrict__ off, const int* __restrict__ rank,
    int* __restrict__ csr_rows)
{
    int b = blockIdx.x;
    if (b < A_BLKS) {
        a_body(b, h_bf, att_src, att_dst, a_src, a_dst);
    } else {
        int bb = b - A_BLKS;
        fill_body(bb / FILL_BLKS, bb % FILL_BLKS, e0, e1, e2, off, rank, csr_rows);
    }
}

// ---------------------------------------------------------------------------
// Pull body (round-9 half-wave, 20 VGPR, occupancy ~82%).
// ---------------------------------------------------------------------------
__device__ __forceinline__ void pull_body(
    int bx, int r,
    const unsigned short* __restrict__ h_bf, const float* __restrict__ a_src,
    const float* __restrict__ a_dst, const int* __restrict__ cnt,
    const int* __restrict__ off, const int* __restrict__ csr_rows,
    unsigned int* __restrict__ outs_bf)
{
    int tid = threadIdx.x;
    int wave = tid >> 6, lane = tid & 63;
    int half = lane >> 5, hl = lane & 31;
    int hd = hl >> 2;
    const size_t rbase = (size_t)r * N_NODES;
    const int CSR_LAST = R_REL * E_EDGES - 1;

    int nb = (bx * 8 + wave * 2 + half) * 4;

    int deg4[4], dm1[4], st4[4];
    float adv[4];
    int kmax = 0;
    #pragma unroll
    for (int i = 0; i < 4; ++i) {
        size_t rn = rbase + (nb + i);
        deg4[i] = cnt[rn];
        st4[i]  = off[rn];
        dm1[i]  = max(deg4[i] - 1, 0);
        adv[i]  = a_dst[rn * 8 + hd];
        kmax = max(kmax, deg4[i]);
    }
    float acc[4][4] = {};
    float den[4] = {0.f, 0.f, 0.f, 0.f};

    for (int k = 0; k < kmax; k += 2) {
        int rowA[4], rowB[4];
        #pragma unroll
        for (int i = 0; i < 4; ++i) {
            int kA = min(k, dm1[i]), kB = min(k + 1, dm1[i]);
            rowA[i] = csr_rows[min(st4[i] + kA, CSR_LAST)];
            rowB[i] = csr_rows[min(st4[i] + kB, CSR_LAST)];
        }
        float aA[4], aB[4];
        u32x2 hA[4], hB[4];
        #pragma unroll
        for (int i = 0; i < 4; ++i) {
            aA[i] = a_src[(rbase + rowA[i]) * 8 + hd];
            aB[i] = a_src[(rbase + rowB[i]) * 8 + hd];
            hA[i] = *(const u32x2*)(h_bf + (size_t)rowA[i] * 128 + 4 * hl);
            hB[i] = *(const u32x2*)(h_bf + (size_t)rowB[i] * 128 + 4 * hl);
        }
        #pragma unroll
        for (int i = 0; i < 4; ++i) {
            float eA = __expf(lrelu(aA[i] + adv[i]));
            float eB = __expf(lrelu(aB[i] + adv[i]));
            eA = (k     < deg4[i]) ? eA : 0.f;
            eB = (k + 1 < deg4[i]) ? eB : 0.f;
            acc[i][0] += eA * bf_lo(hA[i][0]);
            acc[i][1] += eA * bf_hi(hA[i][0]);
            acc[i][2] += eA * bf_lo(hA[i][1]);
            acc[i][3] += eA * bf_hi(hA[i][1]);
            den[i]    += eA;
            acc[i][0] += eB * bf_lo(hB[i][0]);
            acc[i][1] += eB * bf_hi(hB[i][0]);
            acc[i][2] += eB * bf_lo(hB[i][1]);
            acc[i][3] += eB * bf_hi(hB[i][1]);
            den[i]    += eB;
        }
    }
    #pragma unroll
    for (int i = 0; i < 4; ++i) {
        float inv = 1.f / (den[i] + 1e-16f);
        float o0 = fmaxf(acc[i][0] * inv, 0.f);
        float o1 = fmaxf(acc[i][1] * inv, 0.f);
        float o2 = fmaxf(acc[i][2] * inv, 0.f);
        float o3 = fmaxf(acc[i][3] * inv, 0.f);
        u32x2 p;
        p[0] = (unsigned)(unsigned short)f2bf(o0) | ((unsigned)(unsigned short)f2bf(o1) << 16);
        p[1] = (unsigned)(unsigned short)f2bf(o2) | ((unsigned)(unsigned short)f2bf(o3) << 16);
        *(u32x2*)(outs_bf + (size_t)(nb + i) * 64 + 2 * hl) = p;
    }
}

// ---------------------------------------------------------------------------
// Semantic body (MFMA). unroll 1 on tj to fit the (256,6) cap when riding.
// ---------------------------------------------------------------------------
__device__ __forceinline__ void semantic_body(
    int bx, const unsigned short* __restrict__ outs_bf,
    const short* __restrict__ kwB, const short* __restrict__ linB,
    const float* __restrict__ kb,
    float* __restrict__ proj_out, float* __restrict__ redpart, int r)
{
    __shared__ float sh[4][128];
    int wave = threadIdx.x >> 6, lane = threadIdx.x & 63;
    int row16 = lane & 15, kq = lane >> 4;
    const size_t rbase = (size_t)r * N_NODES;

    float kbv[8];
    #pragma unroll
    for (int tj = 0; tj < 8; ++tj) kbv[tj] = kb[tj * 16 + row16];
    float red_acc[8] = {0.f,0.f,0.f,0.f,0.f,0.f,0.f,0.f};

    for (int b = bx * 4 + wave; b < NBATCH; b += SEMBLK * 4) {
        int nbase = b * 16;
        bf16x8 A[4];
        #pragma unroll
        for (int tk = 0; tk < 4; ++tk)
            A[tk] = *(const bf16x8*)(outs_bf + (size_t)(nbase + row16) * 128 + tk * 32 + kq * 8);

        #pragma unroll 1
        for (int tj = 0; tj < 8; ++tj) {
            f32x4 c = {0.f, 0.f, 0.f, 0.f};
            #pragma unroll
            for (int tk = 0; tk < 4; ++tk) {
                bf16x8 B = *(const bf16x8*)(kwB + ((size_t)(tj * 4 + tk) * 64 + lane) * 8);
                c = __builtin_amdgcn_mfma_f32_16x16x32_bf16(A[tk], B, c, 0, 0, 0);
            }
            float ts = 0.f;
            #pragma unroll
            for (int m = 0; m < 4; ++m) {
                float s = c[m] + kbv[tj];
                float ex = __expf(2.f * s);
                ts += 1.f - 2.f / (ex + 1.f);
            }
            red_acc[tj] += ts;
        }
        {
            f32x4 c = {0.f, 0.f, 0.f, 0.f};
            #pragma unroll
            for (int tk = 0; tk < 4; ++tk) {
                bf16x8 B = *(const bf16x8*)(linB + ((size_t)tk * 64 + lane) * 8);
                c = __builtin_amdgcn_mfma_f32_16x16x32_bf16(A[tk], B, c, 0, 0, 0);
            }
            if (row16 < 4) {
                #pragma unroll
                for (int m = 0; m < 4; ++m) {
                    int n = nbase + kq * 4 + m;
                    proj_out[(rbase + n) * 4 + row16] = c[m];
                }
            }
        }
    }

    #pragma unroll
    for (int tj = 0; tj < 8; ++tj) {
        float v = red_acc[tj];
        v += __shfl_xor(v, 16);
        v += __shfl_xor(v, 32);
        if (lane < 16) sh[wave][tj * 16 + lane] = v;
    }
    __syncthreads();
    int t = threadIdx.x;
    if (t < 128) {
        float p = sh[0][t] + sh[1][t] + sh[2][t] + sh[3][t];
        redpart[((size_t)r * SEMBLK + bx) * 128 + t] = p;
    }
}

// --------------------------- kernel wrappers -------------------------------
__global__ __launch_bounds__(256) void pull_kernel(
    const unsigned short* __restrict__ h_bf, const float* __restrict__ a_src,
    const float* __restrict__ a_dst, const int* __restrict__ cnt,
    const int* __restrict__ off, const int* __restrict__ csr_rows,
    unsigned int* __restrict__ outs_bf, int r)
{
    pull_body(blockIdx.x, r, h_bf, a_src, a_dst, cnt, off, csr_rows, outs_bf);
}

__global__ __launch_bounds__(256) void semantic_kernel(
    const unsigned short* __restrict__ outs_bf,
    const short* __restrict__ kwB, const short* __restrict__ linB,
    const float* __restrict__ kb,
    float* __restrict__ proj_out, float* __restrict__ redpart, int r)
{
    semantic_body(blockIdx.x, outs_bf, kwB, linB, kb, proj_out, redpart, r);
}

// FUSED pull(r=0) + fill(r=1,2)   [both low VGPR]
__global__ __launch_bounds__(256) void pull0_fill12_kernel(
    const unsigned short* __restrict__ h_bf, const float* __restrict__ a_src,
    const float* __restrict__ a_dst, const int* __restrict__ cnt,
    const int* __restrict__ off, const int* __restrict__ csr_rows,
    unsigned int* __restrict__ outs_bf,
    const int* __restrict__ e0, const int* __restrict__ e1, const int* __restrict__ e2,
    const int* __restrict__ rank, int* __restrict__ csr_w)
{
    int b = blockIdx.x;
    if (b < PULL_BLKS) {
        pull_body(b, 0, h_bf, a_src, a_dst, cnt, off, csr_rows, outs_bf);
    } else {
        int bb = b - PULL_BLKS;
        fill_body(1 + bb / FILL_BLKS, bb % FILL_BLKS, e0, e1, e2, off, rank, csr_w);
    }
}

// FUSED pull(rpull)->outsW + semantic(rsem)<-outsR (different buffers!).
// (256,6): pull (20 VGPR) unaffected; sem is the capped rider.
__global__ __launch_bounds__(256, 6) void pull_sem_kernel(
    const unsigned short* __restrict__ h_bf, const float* __restrict__ a_src,
    const float* __restrict__ a_dst, const int* __restrict__ cnt,
    const int* __restrict__ off, const int* __restrict__ csr_rows,
    unsigned int* __restrict__ outsW, const unsigned short* __restrict__ outsR,
    const short* __restrict__ kwB, const short* __restrict__ linB,
    const float* __restrict__ kb, float* __restrict__ proj_out,
    float* __restrict__ redpart, int rpull, int rsem)
{
    int b = blockIdx.x;
    if (b < PULL_BLKS) {
        pull_body(b, rpull, h_bf, a_src, a_dst, cnt, off, csr_rows, outsW);
    } else {
        semantic_body(b - PULL_BLKS, outsR, kwB, linB, kb, proj_out, redpart, rsem);
    }
}

// ---------------------------------------------------------------------------
__global__ __launch_bounds__(256) void redreduce_kernel(
    const float* __restrict__ redpart, float* __restrict__ red)
{
    __shared__ float sh[2][128];
    int r = blockIdx.x;
    int t = threadIdx.x;
    int j = t & 127, half = t >> 7;
    float s = 0.f;
    for (int b = half; b < SEMBLK; b += 2)
        s += redpart[((size_t)r * SEMBLK + b) * 128 + j];
    sh[half][j] = s;
    __syncthreads();
    if (t < 128) red[r * 128 + t] = sh[0][t] + sh[1][t];
}

__global__ void attn_kernel(const float* __restrict__ red, const float* __restrict__ q,
                            float* __restrict__ attn)
{
    int lane = threadIdx.x;
    float p[3];
    #pragma unroll
    for (int r = 0; r < 3; ++r) {
        float v = q[lane] * red[r * 128 + lane] + q[lane + 64] * red[r * 128 + lane + 64];
        for (int sft = 32; sft; sft >>= 1) v += __shfl_down(v, sft);
        p[r] = v;
    }
    if (lane == 0) {
        float s0 = p[0] / (float)N_NODES;
        float s1 = p[1] / (float)N_NODES;
        float s2 = p[2] / (float)N_NODES;
        float m = fmaxf(s0, fmaxf(s1, s2));
        float e0 = __expf(s0 - m), e1 = __expf(s1 - m), e2 = __expf(s2 - m);
        float inv = 1.f / (e0 + e1 + e2);
        attn[0] = e0 * inv; attn[1] = e1 * inv; attn[2] = e2 * inv;
    }
}

__global__ __launch_bounds__(256) void final_kernel(
    const float* __restrict__ proj_out, const float* __restrict__ attn,
    const float* __restrict__ lb, float* __restrict__ out)
{
    int i = blockIdx.x * 256 + threadIdx.x;
    if (i >= N_NODES * 4) return;
    int o = i & 3;
    out[i] = attn[0] * proj_out[i]
           + attn[1] * proj_out[(size_t)N_NODES * 4 + i]
           + attn[2] * proj_out[(size_t)2 * N_NODES * 4 + i]
           + lb[o];
}

extern "C" void kernel_launch(void* const* d_in, const int* in_sizes, int n_in,
                              void* d_out, int out_size, void* d_ws, size_t ws_size,
                              hipStream_t stream)
{
    const float* x       = (const float*)d_in[0];
    const int*   e0      = (const int*)d_in[1];
    const int*   e1      = (const int*)d_in[2];
    const int*   e2      = (const int*)d_in[3];
    const float* pw      = (const float*)d_in[4];
    const float* pb      = (const float*)d_in[5];
    const float* att_src = (const float*)d_in[6];
    const float* att_dst = (const float*)d_in[7];
    const float* kw      = (const float*)d_in[8];
    const float* kb      = (const float*)d_in[9];
    const float* q       = (const float*)d_in[10];
    const float* lw      = (const float*)d_in[11];
    const float* lb      = (const float*)d_in[12];
    float* out = (float*)d_out;

    // Layout (float units). Base ~90.9 MB; +rank 12 MB (P1); +outs2 25.6 MB (P2).
    float* ws = (float*)d_ws;
    unsigned short* h_bf    = (unsigned short*)ws;     // 12.8M ushort
    float*          a_src   = ws + 6400000;
    float*          a_dst   = ws + 8800000;
    unsigned int*   outs0   = (unsigned int*)(ws + 11200000); // 6.4M u32
    float*          proj_out= ws + 17600000;
    float*          red     = ws + 18800000;
    float*          attn    = ws + 18800384;
    short*          kwB     = (short*)(ws + 18800388);
    short*          pwB     = (short*)(ws + 18808580);
    short*          linB    = (short*)(ws + 18816772);
    int*            cnt     = (int*)(ws + 18817796);
    int*            off     = (int*)(ws + 19117796);
    int*            csr_rows= (int*)(ws + 19417796);
    int*            bsums   = (int*)(ws + 22417796);
    int*            bpre    = (int*)(ws + 22418969);
    float*          redpart = ws + 22420224;           // ..22,720,512

    const size_t P1_NEED = (size_t)(22720512 + 3000000) * 4;            // ~102.9 MB
    const size_t P2_NEED = (size_t)(22720512 + 3000000 + 6400000) * 4;  // ~128.5 MB
    bool p2 = ws_size >= P2_NEED;
    bool p1 = ws_size >= P1_NEED;
    int* rank = p1 ? (int*)(ws + 22720512) : (int*)outs0;  // alias if tight
    unsigned int* outs1 = p2 ? (unsigned int*)(ws + 25720512) : outs0;

    hipMemsetAsync(cnt, 0, 300000 * sizeof(int), stream);

    prep_kernel<<<dim3(136), dim3(256), 0, stream>>>(kw, pw, lw, kwB, pwB, linB);
    count_proj_kernel<<<dim3(CNT_BLKS + PROJ_BLKS), dim3(256), 0, stream>>>(
        e0, e1, e2, cnt, rank, x, pwB, pb, h_bf);
    bsum_kernel<<<dim3(NBLK, 3), dim3(256), 0, stream>>>(cnt, bsums);
    bscan_kernel<<<dim3(3), dim3(512), 0, stream>>>(bsums, bpre);
    offwrite_kernel<<<dim3(NBLK, 3), dim3(256), 0, stream>>>(cnt, bpre, off);

    if (p2) {
        // a + fill0; pull0+fill12; sem0 rides pull1 (outs dbuf); sem1 rides pull2.
        a_fill_kernel<<<dim3(A_BLKS + FILL_BLKS), dim3(256), 0, stream>>>(
            h_bf, att_src, att_dst, a_src, a_dst, e0, e1, e2, off, rank, csr_rows);
        pull0_fill12_kernel<<<dim3(PULL_BLKS + 2 * FILL_BLKS), dim3(256), 0, stream>>>(
            h_bf, a_src, a_dst, cnt, off, csr_rows, outs0,
            e0, e1, e2, rank, csr_rows);
        pull_sem_kernel<<<dim3(PULL_BLKS + SEMBLK), dim3(256), 0, stream>>>(
            h_bf, a_src, a_dst, cnt, off, csr_rows, outs1,
            (const unsigned short*)outs0, kwB, linB, kb, proj_out, redpart, 1, 0);
        pull_sem_kernel<<<dim3(PULL_BLKS + SEMBLK), dim3(256), 0, stream>>>(
            h_bf, a_src, a_dst, cnt, off, csr_rows, outs0,
            (const unsigned short*)outs1, kwB, linB, kb, proj_out, redpart, 2, 1);
        semantic_kernel<<<dim3(SEMBLK), dim3(256), 0, stream>>>(
            (const unsigned short*)outs0, kwB, linB, kb, proj_out, redpart, 2);
    } else if (p1) {
        a_fill_kernel<<<dim3(A_BLKS + FILL_BLKS), dim3(256), 0, stream>>>(
            h_bf, att_src, att_dst, a_src, a_dst, e0, e1, e2, off, rank, csr_rows);
        pull0_fill12_kernel<<<dim3(PULL_BLKS + 2 * FILL_BLKS), dim3(256), 0, stream>>>(
            h_bf, a_src, a_dst, cnt, off, csr_rows, outs0,
            e0, e1, e2, rank, csr_rows);
        semantic_kernel<<<dim3(SEMBLK), dim3(256), 0, stream>>>(
            (const unsigned short*)outs0, kwB, linB, kb, proj_out, redpart, 0);
        for (int r = 1; r < 3; ++r) {
            pull_kernel<<<dim3(PULL_BLKS), dim3(256), 0, stream>>>(
                h_bf, a_src, a_dst, cnt, off, csr_rows, outs0, r);
            semantic_kernel<<<dim3(SEMBLK), dim3(256), 0, stream>>>(
                (const unsigned short*)outs0, kwB, linB, kb, proj_out, redpart, r);
        }
    } else {
        // rank aliases outs0: all fills BEFORE any pull.
        a_fill_kernel<<<dim3(A_BLKS + 3 * FILL_BLKS), dim3(256), 0, stream>>>(
            h_bf, att_src, att_dst, a_src, a_dst, e0, e1, e2, off, rank, csr_rows);
        for (int r = 0; r < 3; ++r) {
            pull_kernel<<<dim3(PULL_BLKS), dim3(256), 0, stream>>>(
                h_bf, a_src, a_dst, cnt, off, csr_rows, outs0, r);
            semantic_kernel<<<dim3(SEMBLK), dim3(256), 0, stream>>>(
                (const unsigned short*)outs0, kwB, linB, kb, proj_out, redpart, r);
        }
    }

    redreduce_kernel<<<dim3(3), dim3(256), 0, stream>>>(redpart, red);
    attn_kernel<<<dim3(1), dim3(64), 0, stream>>>(red, q, attn);
    final_kernel<<<dim3(1563), dim3(256), 0, stream>>>(proj_out, attn, lb, out);
}

// Round 13
// 528.964 us; speedup vs baseline: 1.0735x; 1.0735x over previous
//
#include <hip/hip_runtime.h>

#define N_NODES 100000
#define E_EDGES 1000000
#define R_REL   3
#define NBATCH  6250          // N_NODES / 16
#define NBLK    391           // ceil(N_NODES / 256)
#define SEMBLK  782           // semantic grid blocks
#define CNT_BLKS  11721       // 3907 * 3
#define PROJ_BLKS 391
#define A_BLKS    3125        // 800000 / 256
#define FILL_BLKS 3907
#define PULL_BLKS 3125

using bf16x8 = __attribute__((ext_vector_type(8))) short;
using f32x4  = __attribute__((ext_vector_type(4))) float;
using u32x2  = __attribute__((ext_vector_type(2))) unsigned int;

__device__ __forceinline__ float lrelu(float x) { return fmaxf(x, 0.2f * x); }

__device__ __forceinline__ short f2bf(float f) {   // RNE f32->bf16
    unsigned u = __builtin_bit_cast(unsigned, f);
    u += 0x7FFFu + ((u >> 16) & 1u);
    return (short)(u >> 16);
}
__device__ __forceinline__ float bf_lo(unsigned u) {
    return __builtin_bit_cast(float, u << 16);
}
__device__ __forceinline__ float bf_hi(unsigned u) {
    return __builtin_bit_cast(float, u & 0xFFFF0000u);
}
__device__ __forceinline__ float bf2f(unsigned short u) {
    return __builtin_bit_cast(float, ((unsigned)u) << 16);
}

// ---------------------------------------------------------------------------
// Bake bf16 B-fragments for 16x16x32 MFMA (kw, pw full 128x128; lin 4x128).
// ---------------------------------------------------------------------------
__global__ __launch_bounds__(256) void prep_kernel(
    const float* __restrict__ kw, const float* __restrict__ pw,
    const float* __restrict__ lw,
    short* __restrict__ kwB, short* __restrict__ pwB, short* __restrict__ linB)
{
    int idx = blockIdx.x * 256 + threadIdx.x;
    int which, rem;
    if      (idx < 16384) { which = 0; rem = idx; }
    else if (idx < 32768) { which = 1; rem = idx - 16384; }
    else if (idx < 34816) { which = 2; rem = idx - 32768; }
    else return;
    int e = rem & 7, lane = (rem >> 3) & 63, t = rem >> 9;
    int tj = (which == 2) ? 0 : (t >> 2);
    int tk = (which == 2) ? t : (t & 3);
    int j = tj * 16 + (lane & 15);
    int k = tk * 32 + (lane >> 4) * 8 + e;
    const float* src = (which == 0) ? kw : (which == 1) ? pw : lw;
    float v = (which == 2 && j >= 4) ? 0.f : src[j * 128 + k];
    short* dst = (which == 0) ? kwB : (which == 1) ? pwB : linB;
    dst[rem] = f2bf(v);
}

// ---------------------------------------------------------------------------
// proj body (MFMA, full unroll — round-11 proven version).
// ---------------------------------------------------------------------------
__device__ __forceinline__ void proj_body(
    int bx, const float* __restrict__ x, const short* __restrict__ pwB,
    const float* __restrict__ pb, unsigned short* __restrict__ h_bf)
{
    int wave = threadIdx.x >> 6, lane = threadIdx.x & 63;
    int row16 = lane & 15, kq = lane >> 4;
    for (int b = bx * 4 + wave; b < NBATCH; b += PROJ_BLKS * 4) {
        int nbase = b * 16;
        bf16x8 A[4];
        #pragma unroll
        for (int tk = 0; tk < 4; ++tk) {
            const float* px = x + (size_t)(nbase + row16) * 128 + tk * 32 + kq * 8;
            f32x4 lo = *(const f32x4*)px;
            f32x4 hi = *(const f32x4*)(px + 4);
            bf16x8 a;
            a[0] = f2bf(lo[0]); a[1] = f2bf(lo[1]); a[2] = f2bf(lo[2]); a[3] = f2bf(lo[3]);
            a[4] = f2bf(hi[0]); a[5] = f2bf(hi[1]); a[6] = f2bf(hi[2]); a[7] = f2bf(hi[3]);
            A[tk] = a;
        }
        #pragma unroll
        for (int tj = 0; tj < 8; ++tj) {
            f32x4 c = {0.f, 0.f, 0.f, 0.f};
            #pragma unroll
            for (int tk = 0; tk < 4; ++tk) {
                bf16x8 B = *(const bf16x8*)(pwB + ((size_t)(tj * 4 + tk) * 64 + lane) * 8);
                c = __builtin_amdgcn_mfma_f32_16x16x32_bf16(A[tk], B, c, 0, 0, 0);
            }
            int j = tj * 16 + row16;
            float bias = pb[j];
            #pragma unroll
            for (int m = 0; m < 4; ++m) {
                int n = nbase + kq * 4 + m;
                h_bf[(size_t)n * 128 + j] = (unsigned short)f2bf(c[m] + bias);
            }
        }
    }
}

// FUSED count + proj (uncapped — round-11 proven; both at the same BW pipe,
// cost is additive ~146us; the cap experiment of round 12 only hurt).
__global__ __launch_bounds__(256) void count_proj_kernel(
    const int* __restrict__ e0, const int* __restrict__ e1, const int* __restrict__ e2,
    int* __restrict__ cnt, int* __restrict__ rank,
    const float* __restrict__ x, const short* __restrict__ pwB,
    const float* __restrict__ pb, unsigned short* __restrict__ h_bf)
{
    int b = blockIdx.x;
    if (b < CNT_BLKS) {
        int r = b / 3907, eb = b % 3907;
        const int* ei = (r == 0) ? e0 : (r == 1) ? e1 : e2;
        int e = eb * 256 + threadIdx.x;
        if (e < E_EDGES) {
            int k = atomicAdd(&cnt[r * N_NODES + ei[E_EDGES + e]], 1);
            rank[(size_t)r * E_EDGES + e] = k;
        }
    } else {
        proj_body(b - CNT_BLKS, x, pwB, pb, h_bf);
    }
}

// --------------------------- scans ------------------------------------
__global__ __launch_bounds__(256) void bsum_kernel(
    const int* __restrict__ cnt, int* __restrict__ bsums)
{
    __shared__ int sh[256];
    int r = blockIdx.y, b = blockIdx.x, t = threadIdx.x;
    int i = b * 256 + t;
    sh[t] = (i < N_NODES) ? cnt[r * N_NODES + i] : 0;
    __syncthreads();
    for (int d = 128; d > 0; d >>= 1) {
        if (t < d) sh[t] += sh[t + d];
        __syncthreads();
    }
    if (t == 0) bsums[r * NBLK + b] = sh[0];
}

__global__ __launch_bounds__(512) void bscan_kernel(
    const int* __restrict__ bsums, int* __restrict__ bpre)
{
    __shared__ int sh[512];
    int r = blockIdx.x, t = threadIdx.x;
    sh[t] = (t < NBLK) ? bsums[r * NBLK + t] : 0;
    __syncthreads();
    for (int d = 1; d < 512; d <<= 1) {
        int v = (t >= d) ? sh[t - d] : 0;
        __syncthreads();
        sh[t] += v;
        __syncthreads();
    }
    if (t < NBLK) bpre[r * NBLK + t] = (t > 0) ? sh[t - 1] : 0;
}

__global__ __launch_bounds__(256) void offwrite_kernel(
    const int* __restrict__ cnt, const int* __restrict__ bpre,
    int* __restrict__ off)
{
    __shared__ int sh[256];
    int r = blockIdx.y, b = blockIdx.x, t = threadIdx.x;
    int i = b * 256 + t;
    int c = (i < N_NODES) ? cnt[r * N_NODES + i] : 0;
    sh[t] = c;
    __syncthreads();
    for (int d = 1; d < 256; d <<= 1) {
        int v = (t >= d) ? sh[t - d] : 0;
        __syncthreads();
        sh[t] += v;
        __syncthreads();
    }
    if (i < N_NODES)
        off[r * N_NODES + i] = r * E_EDGES + bpre[r * NBLK + b] + (sh[t] - c);
}

// --------------------------- a / fill bodies -------------------------------
__device__ __forceinline__ void a_body(
    int bx, const unsigned short* __restrict__ h_bf,
    const float* __restrict__ att_src, const float* __restrict__ att_dst,
    float* __restrict__ a_src, float* __restrict__ a_dst)
{
    int idx = bx * 256 + threadIdx.x;
    if (idx >= N_NODES * 8) return;
    int n = idx >> 3, hd = idx & 7;
    float hv[16];
    const unsigned short* ph = h_bf + (size_t)n * 128 + hd * 16;
    #pragma unroll
    for (int d = 0; d < 16; ++d) hv[d] = bf2f(ph[d]);
    #pragma unroll
    for (int r = 0; r < 3; ++r) {
        float vs = 0.f, vd = 0.f;
        #pragma unroll
        for (int d = 0; d < 16; ++d) {
            vs += hv[d] * att_src[(r * 8 + hd) * 16 + d];
            vd += hv[d] * att_dst[(r * 8 + hd) * 16 + d];
        }
        a_src[((size_t)r * N_NODES + n) * 8 + hd] = vs;
        a_dst[((size_t)r * N_NODES + n) * 8 + hd] = vd;
    }
}

__device__ __forceinline__ void fill_body(
    int r, int eb,
    const int* __restrict__ e0, const int* __restrict__ e1, const int* __restrict__ e2,
    const int* __restrict__ off, const int* __restrict__ rank,
    int* __restrict__ csr_rows)
{
    const int* ei = (r == 0) ? e0 : (r == 1) ? e1 : e2;
    int e = eb * 256 + threadIdx.x;
    if (e >= E_EDGES) return;
    int col = ei[E_EDGES + e];
    int pos = off[r * N_NODES + col] + rank[(size_t)r * E_EDGES + e];
    csr_rows[pos] = ei[e];
}

// FUSED a + fill(nfill relations encoded in grid size). Both <=48 VGPR.
__global__ __launch_bounds__(256) void a_fill_kernel(
    const unsigned short* __restrict__ h_bf, const float* __restrict__ att_src,
    const float* __restrict__ att_dst, float* __restrict__ a_src,
    float* __restrict__ a_dst,
    const int* __restrict__ e0, const int* __restrict__ e1, const int* __restrict__ e2,
    const int* __restrict__ off, const int* __restrict__ rank,
    int* __restrict__ csr_rows)
{
    int b = blockIdx.x;
    if (b < A_BLKS) {
        a_body(b, h_bf, att_src, att_dst, a_src, a_dst);
    } else {
        int bb = b - A_BLKS;
        fill_body(bb / FILL_BLKS, bb % FILL_BLKS, e0, e1, e2, off, rank, csr_rows);
    }
}

// ---------------------------------------------------------------------------
// Pull body, 2-edge unroll (round-9 proven; 20 VGPR, ~82% occupancy).
// ---------------------------------------------------------------------------
__device__ __forceinline__ void pull_body(
    int bx, int r,
    const unsigned short* __restrict__ h_bf, const float* __restrict__ a_src,
    const float* __restrict__ a_dst, const int* __restrict__ cnt,
    const int* __restrict__ off, const int* __restrict__ csr_rows,
    unsigned int* __restrict__ outs_bf)
{
    int tid = threadIdx.x;
    int wave = tid >> 6, lane = tid & 63;
    int half = lane >> 5, hl = lane & 31;
    int hd = hl >> 2;
    const size_t rbase = (size_t)r * N_NODES;
    const int CSR_LAST = R_REL * E_EDGES - 1;

    int nb = (bx * 8 + wave * 2 + half) * 4;

    int deg4[4], dm1[4], st4[4];
    float adv[4];
    int kmax = 0;
    #pragma unroll
    for (int i = 0; i < 4; ++i) {
        size_t rn = rbase + (nb + i);
        deg4[i] = cnt[rn];
        st4[i]  = off[rn];
        dm1[i]  = max(deg4[i] - 1, 0);
        adv[i]  = a_dst[rn * 8 + hd];
        kmax = max(kmax, deg4[i]);
    }
    float acc[4][4] = {};
    float den[4] = {0.f, 0.f, 0.f, 0.f};

    for (int k = 0; k < kmax; k += 2) {
        int rowA[4], rowB[4];
        #pragma unroll
        for (int i = 0; i < 4; ++i) {
            int kA = min(k, dm1[i]), kB = min(k + 1, dm1[i]);
            rowA[i] = csr_rows[min(st4[i] + kA, CSR_LAST)];
            rowB[i] = csr_rows[min(st4[i] + kB, CSR_LAST)];
        }
        float aA[4], aB[4];
        u32x2 hA[4], hB[4];
        #pragma unroll
        for (int i = 0; i < 4; ++i) {
            aA[i] = a_src[(rbase + rowA[i]) * 8 + hd];
            aB[i] = a_src[(rbase + rowB[i]) * 8 + hd];
            hA[i] = *(const u32x2*)(h_bf + (size_t)rowA[i] * 128 + 4 * hl);
            hB[i] = *(const u32x2*)(h_bf + (size_t)rowB[i] * 128 + 4 * hl);
        }
        #pragma unroll
        for (int i = 0; i < 4; ++i) {
            float eA = __expf(lrelu(aA[i] + adv[i]));
            float eB = __expf(lrelu(aB[i] + adv[i]));
            eA = (k     < deg4[i]) ? eA : 0.f;
            eB = (k + 1 < deg4[i]) ? eB : 0.f;
            acc[i][0] += eA * bf_lo(hA[i][0]);
            acc[i][1] += eA * bf_hi(hA[i][0]);
            acc[i][2] += eA * bf_lo(hA[i][1]);
            acc[i][3] += eA * bf_hi(hA[i][1]);
            den[i]    += eA;
            acc[i][0] += eB * bf_lo(hB[i][0]);
            acc[i][1] += eB * bf_hi(hB[i][0]);
            acc[i][2] += eB * bf_lo(hB[i][1]);
            acc[i][3] += eB * bf_hi(hB[i][1]);
            den[i]    += eB;
        }
    }
    #pragma unroll
    for (int i = 0; i < 4; ++i) {
        float inv = 1.f / (den[i] + 1e-16f);
        float o0 = fmaxf(acc[i][0] * inv, 0.f);
        float o1 = fmaxf(acc[i][1] * inv, 0.f);
        float o2 = fmaxf(acc[i][2] * inv, 0.f);
        float o3 = fmaxf(acc[i][3] * inv, 0.f);
        u32x2 p;
        p[0] = (unsigned)(unsigned short)f2bf(o0) | ((unsigned)(unsigned short)f2bf(o1) << 16);
        p[1] = (unsigned)(unsigned short)f2bf(o2) | ((unsigned)(unsigned short)f2bf(o3) << 16);
        *(u32x2*)(outs_bf + (size_t)(nb + i) * 64 + 2 * hl) = p;
    }
}

// ---------------------------------------------------------------------------
// A/B EXPERIMENT ARM: 3-edge unroll pull (+50% memory-level parallelism per
// stream). Used for r=1 only; r=2 keeps the 2-edge control.
// ---------------------------------------------------------------------------
__global__ __launch_bounds__(256) void pull3_kernel(
    const unsigned short* __restrict__ h_bf, const float* __restrict__ a_src,
    const float* __restrict__ a_dst, const int* __restrict__ cnt,
    const int* __restrict__ off, const int* __restrict__ csr_rows,
    unsigned int* __restrict__ outs_bf, int r)
{
    int tid = threadIdx.x;
    int wave = tid >> 6, lane = tid & 63;
    int half = lane >> 5, hl = lane & 31;
    int hd = hl >> 2;
    const size_t rbase = (size_t)r * N_NODES;
    const int CSR_LAST = R_REL * E_EDGES - 1;

    int nb = (blockIdx.x * 8 + wave * 2 + half) * 4;

    int deg4[4], dm1[4], st4[4];
    float adv[4];
    int kmax = 0;
    #pragma unroll
    for (int i = 0; i < 4; ++i) {
        size_t rn = rbase + (nb + i);
        deg4[i] = cnt[rn];
        st4[i]  = off[rn];
        dm1[i]  = max(deg4[i] - 1, 0);
        adv[i]  = a_dst[rn * 8 + hd];
        kmax = max(kmax, deg4[i]);
    }
    float acc[4][4] = {};
    float den[4] = {0.f, 0.f, 0.f, 0.f};

    for (int k = 0; k < kmax; k += 3) {
        int rowA[4], rowB[4], rowC[4];
        #pragma unroll
        for (int i = 0; i < 4; ++i) {
            int kA = min(k, dm1[i]);
            int kB = min(k + 1, dm1[i]);
            int kC = min(k + 2, dm1[i]);
            rowA[i] = csr_rows[min(st4[i] + kA, CSR_LAST)];
            rowB[i] = csr_rows[min(st4[i] + kB, CSR_LAST)];
            rowC[i] = csr_rows[min(st4[i] + kC, CSR_LAST)];
        }
        float aA[4], aB[4], aC[4];
        u32x2 hA[4], hB[4], hC[4];
        #pragma unroll
        for (int i = 0; i < 4; ++i) {
            aA[i] = a_src[(rbase + rowA[i]) * 8 + hd];
            aB[i] = a_src[(rbase + rowB[i]) * 8 + hd];
            aC[i] = a_src[(rbase + rowC[i]) * 8 + hd];
            hA[i] = *(const u32x2*)(h_bf + (size_t)rowA[i] * 128 + 4 * hl);
            hB[i] = *(const u32x2*)(h_bf + (size_t)rowB[i] * 128 + 4 * hl);
            hC[i] = *(const u32x2*)(h_bf + (size_t)rowC[i] * 128 + 4 * hl);
        }
        #pragma unroll
        for (int i = 0; i < 4; ++i) {
            float eA = __expf(lrelu(aA[i] + adv[i]));
            float eB = __expf(lrelu(aB[i] + adv[i]));
            float eC = __expf(lrelu(aC[i] + adv[i]));
            eA = (k     < deg4[i]) ? eA : 0.f;
            eB = (k + 1 < deg4[i]) ? eB : 0.f;
            eC = (k + 2 < deg4[i]) ? eC : 0.f;
            acc[i][0] += eA * bf_lo(hA[i][0]);
            acc[i][1] += eA * bf_hi(hA[i][0]);
            acc[i][2] += eA * bf_lo(hA[i][1]);
            acc[i][3] += eA * bf_hi(hA[i][1]);
            den[i]    += eA;
            acc[i][0] += eB * bf_lo(hB[i][0]);
            acc[i][1] += eB * bf_hi(hB[i][0]);
            acc[i][2] += eB * bf_lo(hB[i][1]);
            acc[i][3] += eB * bf_hi(hB[i][1]);
            den[i]    += eB;
            acc[i][0] += eC * bf_lo(hC[i][0]);
            acc[i][1] += eC * bf_hi(hC[i][0]);
            acc[i][2] += eC * bf_lo(hC[i][1]);
            acc[i][3] += eC * bf_hi(hC[i][1]);
            den[i]    += eC;
        }
    }
    #pragma unroll
    for (int i = 0; i < 4; ++i) {
        float inv = 1.f / (den[i] + 1e-16f);
        float o0 = fmaxf(acc[i][0] * inv, 0.f);
        float o1 = fmaxf(acc[i][1] * inv, 0.f);
        float o2 = fmaxf(acc[i][2] * inv, 0.f);
        float o3 = fmaxf(acc[i][3] * inv, 0.f);
        u32x2 p;
        p[0] = (unsigned)(unsigned short)f2bf(o0) | ((unsigned)(unsigned short)f2bf(o1) << 16);
        p[1] = (unsigned)(unsigned short)f2bf(o2) | ((unsigned)(unsigned short)f2bf(o3) << 16);
        *(u32x2*)(outs_bf + (size_t)(nb + i) * 64 + 2 * hl) = p;
    }
}

// ---------------------------------------------------------------------------
// Semantic body (MFMA, full unroll — proven ~20us).
// ---------------------------------------------------------------------------
__device__ __forceinline__ void semantic_body(
    int bx, const unsigned short* __restrict__ outs_bf,
    const short* __restrict__ kwB, const short* __restrict__ linB,
    const float* __restrict__ kb,
    float* __restrict__ proj_out, float* __restrict__ redpart, int r)
{
    __shared__ float sh[4][128];
    int wave = threadIdx.x >> 6, lane = threadIdx.x & 63;
    int row16 = lane & 15, kq = lane >> 4;
    const size_t rbase = (size_t)r * N_NODES;

    float kbv[8];
    #pragma unroll
    for (int tj = 0; tj < 8; ++tj) kbv[tj] = kb[tj * 16 + row16];
    float red_acc[8] = {0.f,0.f,0.f,0.f,0.f,0.f,0.f,0.f};

    for (int b = bx * 4 + wave; b < NBATCH; b += SEMBLK * 4) {
        int nbase = b * 16;
        bf16x8 A[4];
        #pragma unroll
        for (int tk = 0; tk < 4; ++tk)
            A[tk] = *(const bf16x8*)(outs_bf + (size_t)(nbase + row16) * 128 + tk * 32 + kq * 8);

        #pragma unroll
        for (int tj = 0; tj < 8; ++tj) {
            f32x4 c = {0.f, 0.f, 0.f, 0.f};
            #pragma unroll
            for (int tk = 0; tk < 4; ++tk) {
                bf16x8 B = *(const bf16x8*)(kwB + ((size_t)(tj * 4 + tk) * 64 + lane) * 8);
                c = __builtin_amdgcn_mfma_f32_16x16x32_bf16(A[tk], B, c, 0, 0, 0);
            }
            float ts = 0.f;
            #pragma unroll
            for (int m = 0; m < 4; ++m) {
                float s = c[m] + kbv[tj];
                float ex = __expf(2.f * s);
                ts += 1.f - 2.f / (ex + 1.f);
            }
            red_acc[tj] += ts;
        }
        {
            f32x4 c = {0.f, 0.f, 0.f, 0.f};
            #pragma unroll
            for (int tk = 0; tk < 4; ++tk) {
                bf16x8 B = *(const bf16x8*)(linB + ((size_t)tk * 64 + lane) * 8);
                c = __builtin_amdgcn_mfma_f32_16x16x32_bf16(A[tk], B, c, 0, 0, 0);
            }
            if (row16 < 4) {
                #pragma unroll
                for (int m = 0; m < 4; ++m) {
                    int n = nbase + kq * 4 + m;
                    proj_out[(rbase + n) * 4 + row16] = c[m];
                }
            }
        }
    }

    #pragma unroll
    for (int tj = 0; tj < 8; ++tj) {
        float v = red_acc[tj];
        v += __shfl_xor(v, 16);
        v += __shfl_xor(v, 32);
        if (lane < 16) sh[wave][tj * 16 + lane] = v;
    }
    __syncthreads();
    int t = threadIdx.x;
    if (t < 128) {
        float p = sh[0][t] + sh[1][t] + sh[2][t] + sh[3][t];
        redpart[((size_t)r * SEMBLK + bx) * 128 + t] = p;
    }
}

// --------------------------- kernel wrappers -------------------------------
__global__ __launch_bounds__(256) void pull_kernel(
    const unsigned short* __restrict__ h_bf, const float* __restrict__ a_src,
    const float* __restrict__ a_dst, const int* __restrict__ cnt,
    const int* __restrict__ off, const int* __restrict__ csr_rows,
    unsigned int* __restrict__ outs_bf, int r)
{
    pull_body(blockIdx.x, r, h_bf, a_src, a_dst, cnt, off, csr_rows, outs_bf);
}

__global__ __launch_bounds__(256) void semantic_kernel(
    const unsigned short* __restrict__ outs_bf,
    const short* __restrict__ kwB, const short* __restrict__ linB,
    const float* __restrict__ kb,
    float* __restrict__ proj_out, float* __restrict__ redpart, int r)
{
    semantic_body(blockIdx.x, outs_bf, kwB, linB, kb, proj_out, redpart, r);
}

// FUSED pull(r=0) + fill(r=1,2)   [both low VGPR, different pipes]
__global__ __launch_bounds__(256) void pull0_fill12_kernel(
    const unsigned short* __restrict__ h_bf, const float* __restrict__ a_src,
    const float* __restrict__ a_dst, const int* __restrict__ cnt,
    const int* __restrict__ off, const int* __restrict__ csr_rows,
    unsigned int* __restrict__ outs_bf,
    const int* __restrict__ e0, const int* __restrict__ e1, const int* __restrict__ e2,
    const int* __restrict__ rank, int* __restrict__ csr_w)
{
    int b = blockIdx.x;
    if (b < PULL_BLKS) {
        pull_body(b, 0, h_bf, a_src, a_dst, cnt, off, csr_rows, outs_bf);
    } else {
        int bb = b - PULL_BLKS;
        fill_body(1 + bb / FILL_BLKS, bb % FILL_BLKS, e0, e1, e2, off, rank, csr_w);
    }
}

// ---------------------------------------------------------------------------
__global__ __launch_bounds__(256) void redreduce_kernel(
    const float* __restrict__ redpart, float* __restrict__ red)
{
    __shared__ float sh[2][128];
    int r = blockIdx.x;
    int t = threadIdx.x;
    int j = t & 127, half = t >> 7;
    float s = 0.f;
    for (int b = half; b < SEMBLK; b += 2)
        s += redpart[((size_t)r * SEMBLK + b) * 128 + j];
    sh[half][j] = s;
    __syncthreads();
    if (t < 128) red[r * 128 + t] = sh[0][t] + sh[1][t];
}

__global__ void attn_kernel(const float* __restrict__ red, const float* __restrict__ q,
                            float* __restrict__ attn)
{
    int lane = threadIdx.x;
    float p[3];
    #pragma unroll
    for (int r = 0; r < 3; ++r) {
        float v = q[lane] * red[r * 128 + lane] + q[lane + 64] * red[r * 128 + lane + 64];
        for (int sft = 32; sft; sft >>= 1) v += __shfl_down(v, sft);
        p[r] = v;
    }
    if (lane == 0) {
        float s0 = p[0] / (float)N_NODES;
        float s1 = p[1] / (float)N_NODES;
        float s2 = p[2] / (float)N_NODES;
        float m = fmaxf(s0, fmaxf(s1, s2));
        float e0 = __expf(s0 - m), e1 = __expf(s1 - m), e2 = __expf(s2 - m);
        float inv = 1.f / (e0 + e1 + e2);
        attn[0] = e0 * inv; attn[1] = e1 * inv; attn[2] = e2 * inv;
    }
}

__global__ __launch_bounds__(256) void final_kernel(
    const float* __restrict__ proj_out, const float* __restrict__ attn,
    const float* __restrict__ lb, float* __restrict__ out)
{
    int i = blockIdx.x * 256 + threadIdx.x;
    if (i >= N_NODES * 4) return;
    int o = i & 3;
    out[i] = attn[0] * proj_out[i]
           + attn[1] * proj_out[(size_t)N_NODES * 4 + i]
           + attn[2] * proj_out[(size_t)2 * N_NODES * 4 + i]
           + lb[o];
}

extern "C" void kernel_launch(void* const* d_in, const int* in_sizes, int n_in,
                              void* d_out, int out_size, void* d_ws, size_t ws_size,
                              hipStream_t stream)
{
    const float* x       = (const float*)d_in[0];
    const int*   e0      = (const int*)d_in[1];
    const int*   e1      = (const int*)d_in[2];
    const int*   e2      = (const int*)d_in[3];
    const float* pw      = (const float*)d_in[4];
    const float* pb      = (const float*)d_in[5];
    const float* att_src = (const float*)d_in[6];
    const float* att_dst = (const float*)d_in[7];
    const float* kw      = (const float*)d_in[8];
    const float* kb      = (const float*)d_in[9];
    const float* q       = (const float*)d_in[10];
    const float* lw      = (const float*)d_in[11];
    const float* lb      = (const float*)d_in[12];
    float* out = (float*)d_out;

    // Layout (float units). Base ~90.9 MB; +rank 12 MB if ws allows (P1).
    float* ws = (float*)d_ws;
    unsigned short* h_bf    = (unsigned short*)ws;     // 12.8M ushort
    float*          a_src   = ws + 6400000;
    float*          a_dst   = ws + 8800000;
    unsigned int*   outs0   = (unsigned int*)(ws + 11200000); // 6.4M u32
    float*          proj_out= ws + 17600000;
    float*          red     = ws + 18800000;
    float*          attn    = ws + 18800384;
    short*          kwB     = (short*)(ws + 18800388);
    short*          pwB     = (short*)(ws + 18808580);
    short*          linB    = (short*)(ws + 18816772);
    int*            cnt     = (int*)(ws + 18817796);
    int*            off     = (int*)(ws + 19117796);
    int*            csr_rows= (int*)(ws + 19417796);
    int*            bsums   = (int*)(ws + 22417796);
    int*            bpre    = (int*)(ws + 22418969);
    float*          redpart = ws + 22420224;           // ..22,720,512

    const size_t P1_NEED = (size_t)(22720512 + 3000000) * 4;  // ~102.9 MB
    bool p1 = ws_size >= P1_NEED;
    int* rank = p1 ? (int*)(ws + 22720512) : (int*)outs0;  // alias if tight

    hipMemsetAsync(cnt, 0, 300000 * sizeof(int), stream);

    prep_kernel<<<dim3(136), dim3(256), 0, stream>>>(kw, pw, lw, kwB, pwB, linB);
    count_proj_kernel<<<dim3(CNT_BLKS + PROJ_BLKS), dim3(256), 0, stream>>>(
        e0, e1, e2, cnt, rank, x, pwB, pb, h_bf);
    bsum_kernel<<<dim3(NBLK, 3), dim3(256), 0, stream>>>(cnt, bsums);
    bscan_kernel<<<dim3(3), dim3(512), 0, stream>>>(bsums, bpre);
    offwrite_kernel<<<dim3(NBLK, 3), dim3(256), 0, stream>>>(cnt, bpre, off);

    if (p1) {
        // a + fill0 fused; fill1,2 hidden under pull0; pulls r1 (3-edge A/B
        // arm) and r2 (2-edge control) standalone for clean counters.
        a_fill_kernel<<<dim3(A_BLKS + FILL_BLKS), dim3(256), 0, stream>>>(
            h_bf, att_src, att_dst, a_src, a_dst, e0, e1, e2, off, rank, csr_rows);
        pull0_fill12_kernel<<<dim3(PULL_BLKS + 2 * FILL_BLKS), dim3(256), 0, stream>>>(
            h_bf, a_src, a_dst, cnt, off, csr_rows, outs0,
            e0, e1, e2, rank, csr_rows);
        semantic_kernel<<<dim3(SEMBLK), dim3(256), 0, stream>>>(
            (const unsigned short*)outs0, kwB, linB, kb, proj_out, redpart, 0);
        pull3_kernel<<<dim3(PULL_BLKS), dim3(256), 0, stream>>>(
            h_bf, a_src, a_dst, cnt, off, csr_rows, outs0, 1);
        semantic_kernel<<<dim3(SEMBLK), dim3(256), 0, stream>>>(
            (const unsigned short*)outs0, kwB, linB, kb, proj_out, redpart, 1);
        pull_kernel<<<dim3(PULL_BLKS), dim3(256), 0, stream>>>(
            h_bf, a_src, a_dst, cnt, off, csr_rows, outs0, 2);
        semantic_kernel<<<dim3(SEMBLK), dim3(256), 0, stream>>>(
            (const unsigned short*)outs0, kwB, linB, kb, proj_out, redpart, 2);
    } else {
        // rank aliases outs0: all fills BEFORE any pull.
        a_fill_kernel<<<dim3(A_BLKS + 3 * FILL_BLKS), dim3(256), 0, stream>>>(
            h_bf, att_src, att_dst, a_src, a_dst, e0, e1, e2, off, rank, csr_rows);
        for (int r = 0; r < 3; ++r) {
            pull_kernel<<<dim3(PULL_BLKS), dim3(256), 0, stream>>>(
                h_bf, a_src, a_dst, cnt, off, csr_rows, outs0, r);
            semantic_kernel<<<dim3(SEMBLK), dim3(256), 0, stream>>>(
                (const unsigned short*)outs0, kwB, linB, kb, proj_out, redpart, r);
        }
    }

    redreduce_kernel<<<dim3(3), dim3(256), 0, stream>>>(redpart, red);
    attn_kernel<<<dim3(1), dim3(64), 0, stream>>>(red, q, attn);
    final_kernel<<<dim3(1563), dim3(256), 0, stream>>>(proj_out, attn, lb, out);
}